// Round 1
// baseline (543.831 us; speedup 1.0000x reference)
//
#include <hip/hip_runtime.h>
#include <math.h>

#define B_  2
#define L_  2048
#define D_  512
#define DI_ 1024
#define DS_ 16
#define DC_ 4
#define DR_ 32
#define NX_ 64   // DR + 2*DS
#define NC_ 64   // number of scan chunks
#define CT_ 32   // chunk length (NC_*CT_ == L_)

__device__ __forceinline__ float sigmoidf_(float v) { return 1.f / (1.f + __expf(-v)); }

// C[m,n] = dot(A[m,:K], Bm[n,:K]); writes split across out0 (n<SPLIT) / out1.
template<int K, int N, int SPLIT>
__global__ void gemm_nt_split(const float* __restrict__ A, const float* __restrict__ Bm,
                              float* __restrict__ out0, float* __restrict__ out1) {
    __shared__ float As[64][17];
    __shared__ float Bs[64][17];
    const int bm = blockIdx.y * 64, bn = blockIdx.x * 64;
    const int t = threadIdx.y * 16 + threadIdx.x;
    float acc[4][4] = {};
    for (int k0 = 0; k0 < K; k0 += 16) {
        #pragma unroll
        for (int i = 0; i < 4; i++) {
            int e = t + i * 256;
            int r = e >> 4, c = e & 15;
            As[r][c] = A[(bm + r) * K + k0 + c];
            Bs[r][c] = Bm[(bn + r) * K + k0 + c];
        }
        __syncthreads();
        #pragma unroll
        for (int k = 0; k < 16; k++) {
            float a[4], b[4];
            #pragma unroll
            for (int i = 0; i < 4; i++) a[i] = As[threadIdx.y * 4 + i][k];
            #pragma unroll
            for (int j = 0; j < 4; j++) b[j] = Bs[threadIdx.x * 4 + j][k];
            #pragma unroll
            for (int i = 0; i < 4; i++)
                #pragma unroll
                for (int j = 0; j < 4; j++)
                    acc[i][j] = fmaf(a[i], b[j], acc[i][j]);
        }
        __syncthreads();
    }
    #pragma unroll
    for (int i = 0; i < 4; i++) {
        int m = bm + threadIdx.y * 4 + i;
        int n = bn + threadIdx.x * 4;
        float4 v = make_float4(acc[i][0], acc[i][1], acc[i][2], acc[i][3]);
        if (n < SPLIT) *reinterpret_cast<float4*>(&out0[(size_t)m * SPLIT + n]) = v;
        else           *reinterpret_cast<float4*>(&out1[(size_t)m * (N - SPLIT) + (n - SPLIT)]) = v;
    }
}

__global__ void conv_silu(const float* __restrict__ xi, const float* __restrict__ cw,
                          const float* __restrict__ cb, float* __restrict__ u) {
    int idx = blockIdx.x * 256 + threadIdx.x;        // over B*L*DI
    int d  = idx & (DI_ - 1);
    int bl = idx >> 10;                               // b*L + l
    int l  = bl & (L_ - 1);
    float acc = cb[d];
    #pragma unroll
    for (int k = 0; k < DC_; k++) {
        int lk = l - (DC_ - 1) + k;
        if (lk >= 0) acc = fmaf(xi[(size_t)(bl - (DC_ - 1) + k) * DI_ + d], cw[d * DC_ + k], acc);
    }
    u[idx] = acc * sigmoidf_(acc);
}

__global__ void xproj(const float* __restrict__ u, const float* __restrict__ W,
                      float* __restrict__ xdbl) {
    __shared__ float ur[DI_];
    const int m = blockIdx.x;
    const float* urow = u + (size_t)m * DI_;
    for (int i = threadIdx.x; i < DI_; i += 64) ur[i] = urow[i];
    __syncthreads();
    const int n = threadIdx.x;
    const float* wr = W + (size_t)n * DI_;
    float acc = 0.f;
    for (int k = 0; k < DI_; k += 4) {
        float4 w4 = *reinterpret_cast<const float4*>(wr + k);
        acc = fmaf(ur[k],     w4.x, acc);
        acc = fmaf(ur[k + 1], w4.y, acc);
        acc = fmaf(ur[k + 2], w4.z, acc);
        acc = fmaf(ur[k + 3], w4.w, acc);
    }
    xdbl[(size_t)m * NX_ + n] = acc;
}

__global__ void dt_proj(const float* __restrict__ xdbl, const float* __restrict__ Wdt,
                        const float* __restrict__ bdt, float* __restrict__ delta) {
    __shared__ float dt[DR_];
    int idx = blockIdx.x * 256 + threadIdx.x;
    int m = idx >> 10;
    int d = idx & (DI_ - 1);
    if (threadIdx.x < DR_) dt[threadIdx.x] = xdbl[(size_t)m * NX_ + threadIdx.x];
    __syncthreads();
    float acc = bdt[d];
    const float* wr = Wdt + d * DR_;
    #pragma unroll 8
    for (int r = 0; r < DR_; r++) acc = fmaf(dt[r], wr[r], acc);
    delta[idx] = fmaxf(acc, 0.f) + log1pf(__expf(-fabsf(acc)));   // softplus
}

__global__ void scan_p1(const float* __restrict__ delta, const float* __restrict__ u,
                        const float* __restrict__ xdbl, const float* __restrict__ A_log,
                        float* __restrict__ hz, float* __restrict__ pA) {
    const int d = blockIdx.x * 256 + threadIdx.x;
    const int c = blockIdx.y;
    const int b = blockIdx.z;
    __shared__ float Brow[CT_][DS_];
    for (int i = threadIdx.x; i < CT_ * DS_; i += 256) {
        int t = i >> 4, s = i & 15;
        Brow[t][s] = xdbl[(size_t)(b * L_ + c * CT_ + t) * NX_ + DR_ + s];
    }
    __syncthreads();
    float a[DS_], h[DS_], p[DS_];
    #pragma unroll
    for (int s = 0; s < DS_; s++) {
        a[s] = -__expf(A_log[d * DS_ + s]);
        h[s] = 0.f; p[s] = 1.f;
    }
    size_t base = (size_t)(b * L_ + c * CT_) * DI_ + d;
    for (int t = 0; t < CT_; t++) {
        float dl = delta[base + (size_t)t * DI_];
        float uv = u[base + (size_t)t * DI_];
        float dlu = dl * uv;
        #pragma unroll
        for (int s = 0; s < DS_; s++) {
            float dA = __expf(dl * a[s]);
            p[s] *= dA;
            h[s] = fmaf(dA, h[s], dlu * Brow[t][s]);
        }
    }
    size_t o = ((size_t)(b * NC_ + c) * DI_ + d) * DS_;
    #pragma unroll
    for (int s = 0; s < DS_; s++) { hz[o + s] = h[s]; pA[o + s] = p[s]; }
}

__global__ void carry(const float* __restrict__ hz, const float* __restrict__ pA,
                      float* __restrict__ hin) {
    int idx = blockIdx.x * 256 + threadIdx.x;    // over B*DI*DS
    int b  = idx >> 14;
    int ds = idx & (DI_ * DS_ - 1);
    float h = 0.f;
    for (int c = 0; c < NC_; c++) {
        size_t o = (size_t)(b * NC_ + c) * DI_ * DS_ + ds;
        hin[o] = h;
        h = fmaf(pA[o], h, hz[o]);
    }
}

__global__ void scan_p2(const float* __restrict__ delta, const float* __restrict__ u,
                        const float* __restrict__ xdbl, const float* __restrict__ A_log,
                        const float* __restrict__ hin, const float* __restrict__ z,
                        const float* __restrict__ Dp, float* __restrict__ yv) {
    const int d = blockIdx.x * 256 + threadIdx.x;
    const int c = blockIdx.y;
    const int b = blockIdx.z;
    __shared__ float Brow[CT_][DS_];
    __shared__ float Crow[CT_][DS_];
    for (int i = threadIdx.x; i < CT_ * DS_; i += 256) {
        int t = i >> 4, s = i & 15;
        size_t rb = (size_t)(b * L_ + c * CT_ + t) * NX_;
        Brow[t][s] = xdbl[rb + DR_ + s];
        Crow[t][s] = xdbl[rb + DR_ + DS_ + s];
    }
    __syncthreads();
    float a[DS_], h[DS_];
    size_t ho = ((size_t)(b * NC_ + c) * DI_ + d) * DS_;
    #pragma unroll
    for (int s = 0; s < DS_; s++) {
        a[s] = -__expf(A_log[d * DS_ + s]);
        h[s] = hin[ho + s];
    }
    float Dpd = Dp[d];
    size_t base = (size_t)(b * L_ + c * CT_) * DI_ + d;
    for (int t = 0; t < CT_; t++) {
        float dl = delta[base + (size_t)t * DI_];
        float uv = u[base + (size_t)t * DI_];
        float dlu = dl * uv;
        float acc = 0.f;
        #pragma unroll
        for (int s = 0; s < DS_; s++) {
            float dA = __expf(dl * a[s]);
            h[s] = fmaf(dA, h[s], dlu * Brow[t][s]);
            acc = fmaf(h[s], Crow[t][s], acc);
        }
        float zv = z[base + (size_t)t * DI_];
        float yval = fmaf(uv, Dpd, acc);
        yv[base + (size_t)t * DI_] = yval * (zv * sigmoidf_(zv));
    }
}

__global__ void ln_res(const float* __restrict__ om, const float* __restrict__ x,
                       const float* __restrict__ lw, const float* __restrict__ lb,
                       float* __restrict__ out) {
    const int row = blockIdx.x;                    // b*L
    const float* r = om + (size_t)row * D_;
    float v0 = r[threadIdx.x], v1 = r[threadIdx.x + 256];
    float s = v0 + v1, sq = v0 * v0 + v1 * v1;
    #pragma unroll
    for (int off = 32; off; off >>= 1) {
        s  += __shfl_down(s, off);
        sq += __shfl_down(sq, off);
    }
    __shared__ float ss[4], ssq[4];
    int w = threadIdx.x >> 6;
    if ((threadIdx.x & 63) == 0) { ss[w] = s; ssq[w] = sq; }
    __syncthreads();
    float ts  = ss[0] + ss[1] + ss[2] + ss[3];
    float tsq = ssq[0] + ssq[1] + ssq[2] + ssq[3];
    float mu  = ts * (1.f / 512.f);
    float var = tsq * (1.f / 512.f) - mu * mu;
    float inv = rsqrtf(var + 1e-6f);
    size_t i0 = (size_t)row * D_ + threadIdx.x;
    out[i0]       = x[i0]       + (v0 - mu) * inv * lw[threadIdx.x]       + lb[threadIdx.x];
    out[i0 + 256] = x[i0 + 256] + (v1 - mu) * inv * lw[threadIdx.x + 256] + lb[threadIdx.x + 256];
}

extern "C" void kernel_launch(void* const* d_in, const int* in_sizes, int n_in,
                              void* d_out, int out_size, void* d_ws, size_t ws_size,
                              hipStream_t stream) {
    const float* x      = (const float*)d_in[0];
    const float* W_in   = (const float*)d_in[1];
    const float* conv_w = (const float*)d_in[2];
    const float* conv_b = (const float*)d_in[3];
    const float* W_xp   = (const float*)d_in[4];
    const float* W_dt   = (const float*)d_in[5];
    const float* b_dt   = (const float*)d_in[6];
    const float* A_log  = (const float*)d_in[7];
    const float* Dp     = (const float*)d_in[8];
    const float* W_out  = (const float*)d_in[9];
    const float* ln_w   = (const float*)d_in[10];
    const float* ln_b   = (const float*)d_in[11];
    float* out = (float*)d_out;

    float* ws = (float*)d_ws;
    const size_t NBL = (size_t)B_ * L_ * DI_;          // 4,194,304
    float* xi    = ws;
    float* z     = xi + NBL;
    float* u     = z + NBL;
    float* delta = u + NBL;
    float* yv    = delta + NBL;
    float* xdbl  = yv + NBL;                           // B*L*NX
    float* hz    = xdbl + (size_t)B_ * L_ * NX_;
    float* pAb   = hz + (size_t)B_ * NC_ * DI_ * DS_;
    float* hin   = pAb + (size_t)B_ * NC_ * DI_ * DS_;
    float* om    = xi;                                  // xi dead after conv; reuse

    // 1. in_proj: [4096,512] x [2048,512]^T -> xi | z
    gemm_nt_split<512, 2048, 1024>
        <<<dim3(2048 / 64, 4096 / 64), dim3(16, 16), 0, stream>>>(x, W_in, xi, z);
    // 2. depthwise causal conv + SiLU
    conv_silu<<<(int)(NBL / 256), 256, 0, stream>>>(xi, conv_w, conv_b, u);
    // 3. x_proj: [4096,1024] x [64,1024]^T
    xproj<<<B_ * L_, 64, 0, stream>>>(u, W_xp, xdbl);
    // 4. dt_proj + softplus
    dt_proj<<<(int)(NBL / 256), 256, 0, stream>>>(xdbl, W_dt, b_dt, delta);
    // 5-7. chunked selective scan
    scan_p1<<<dim3(DI_ / 256, NC_, B_), 256, 0, stream>>>(delta, u, xdbl, A_log, hz, pAb);
    carry<<<(B_ * DI_ * DS_) / 256, 256, 0, stream>>>(hz, pAb, hin);
    scan_p2<<<dim3(DI_ / 256, NC_, B_), 256, 0, stream>>>(delta, u, xdbl, A_log, hin, z, Dp, yv);
    // 8. out_proj: [4096,1024] x [512,1024]^T
    gemm_nt_split<1024, 512, 512>
        <<<dim3(512 / 64, 4096 / 64), dim3(16, 16), 0, stream>>>(yv, W_out, om, om);
    // 9. LayerNorm + residual
    ln_res<<<B_ * L_, 256, 0, stream>>>(om, x, ln_w, ln_b, out);
}

// Round 2
// 317.287 us; speedup vs baseline: 1.7140x; 1.7140x over previous
//
#include <hip/hip_runtime.h>
#include <math.h>

#define B_  2
#define L_  2048
#define D_  512
#define DI_ 1024
#define DS_ 16
#define DC_ 4
#define DR_ 32
#define NX_ 64   // DR + 2*DS
#define NC_ 64   // number of scan chunks
#define CT_ 32   // chunk length (NC_*CT_ == L_)

typedef unsigned short u16;
typedef u16   u16x8  __attribute__((ext_vector_type(8)));
typedef __bf16 bf16x8 __attribute__((ext_vector_type(8)));
typedef float  f32x4  __attribute__((ext_vector_type(4)));

__device__ __forceinline__ float sigmoidf_(float v) { return 1.f / (1.f + __expf(-v)); }

__device__ __forceinline__ u16 f2bf(float f) {
    union { float f; unsigned u; } c; c.f = f;
    unsigned u = c.u + 0x7FFFu + ((c.u >> 16) & 1u);
    return (u16)(u >> 16);
}

__global__ void cast_bf16(const float* __restrict__ in, u16* __restrict__ out, int n8) {
    int i = blockIdx.x * 256 + threadIdx.x;
    if (i >= n8) return;
    const float4* p = reinterpret_cast<const float4*>(in) + (size_t)i * 2;
    float4 v0 = p[0], v1 = p[1];
    u16x8 r;
    r[0] = f2bf(v0.x); r[1] = f2bf(v0.y); r[2] = f2bf(v0.z); r[3] = f2bf(v0.w);
    r[4] = f2bf(v1.x); r[5] = f2bf(v1.y); r[6] = f2bf(v1.z); r[7] = f2bf(v1.w);
    reinterpret_cast<u16x8*>(out)[i] = r;
}

// NT bf16 MFMA GEMM: C[m,n] = dot(A[m,:K], B[n,:K]), A:[M][K] bf16, B:[N][K] bf16.
// 128x128 tile, BK=64, 4 waves (2x2), each wave 64x64 via 4x4 frags of 16x16x32.
// LDS XOR-swizzle (byte ^= (row&7)<<4) applied on both sides (pre-swizzled
// global source for global_load_lds + swizzled ds_read).
// Columns [0,N0) go to out0 (row stride N0), [N0,N0+N1) to out1 (stride N1).
template<int K, int N0, int N1>
__global__ __launch_bounds__(256, 2) void gemm_mfma_nt(
    const u16* __restrict__ Ab, const u16* __restrict__ Bb,
    float* __restrict__ out0, float* __restrict__ out1) {
    __shared__ u16 As[128 * 64];
    __shared__ u16 Bs[128 * 64];
    const int bm = blockIdx.y * 128, bn = blockIdx.x * 128;
    const int t = threadIdx.x;
    const int w = t >> 6, l = t & 63;
    const int wm = (w >> 1) * 64, wn = (w & 1) * 64;
    const int lr = l & 15;            // fragment row selector
    const int lk = (l >> 4) * 8;      // fragment k offset

    f32x4 acc[4][4] = {};

    for (int k0 = 0; k0 < K; k0 += 64) {
        #pragma unroll
        for (int i = 0; i < 4; i++) {
            int q  = i * 256 + t;
            int r  = q >> 3;                        // tile row (8 chunks of 16B per row)
            int c0 = ((q ^ r) & 7) << 3;            // pre-swizzled source column
            __builtin_amdgcn_global_load_lds(
                (const __attribute__((address_space(1))) void*)(Ab + (size_t)(bm + r) * K + k0 + c0),
                (__attribute__((address_space(3))) void*)(As + (i * 256 + w * 64) * 8),
                16, 0, 0);
            __builtin_amdgcn_global_load_lds(
                (const __attribute__((address_space(1))) void*)(Bb + (size_t)(bn + r) * K + k0 + c0),
                (__attribute__((address_space(3))) void*)(Bs + (i * 256 + w * 64) * 8),
                16, 0, 0);
        }
        __syncthreads();
        #pragma unroll
        for (int kk = 0; kk < 2; kk++) {
            bf16x8 a[4], b[4];
            #pragma unroll
            for (int m = 0; m < 4; m++) {
                int row  = wm + m * 16 + lr;
                int byte = (row * 128 + (kk * 32 + lk) * 2) ^ ((row & 7) << 4);
                a[m] = *reinterpret_cast<const bf16x8*>(reinterpret_cast<const char*>(As) + byte);
            }
            #pragma unroll
            for (int n = 0; n < 4; n++) {
                int row  = wn + n * 16 + lr;
                int byte = (row * 128 + (kk * 32 + lk) * 2) ^ ((row & 7) << 4);
                b[n] = *reinterpret_cast<const bf16x8*>(reinterpret_cast<const char*>(Bs) + byte);
            }
            #pragma unroll
            for (int m = 0; m < 4; m++)
                #pragma unroll
                for (int n = 0; n < 4; n++)
                    acc[m][n] = __builtin_amdgcn_mfma_f32_16x16x32_bf16(a[m], b[n], acc[m][n], 0, 0, 0);
        }
        __syncthreads();
    }

    // epilogue: C/D layout col = lane&15, row = (lane>>4)*4 + reg
    float* obase = (bn < N0) ? out0 : out1;
    const int stride = (bn < N0) ? N0 : N1;
    const int bcol   = (bn < N0) ? bn : bn - N0;
    #pragma unroll
    for (int m = 0; m < 4; m++) {
        #pragma unroll
        for (int j = 0; j < 4; j++) {
            int row = bm + wm + m * 16 + (l >> 4) * 4 + j;
            #pragma unroll
            for (int n = 0; n < 4; n++)
                obase[(size_t)row * stride + bcol + wn + n * 16 + lr] = acc[m][n][j];
        }
    }
}

__global__ void conv_silu(const float* __restrict__ xi, const float* __restrict__ cw,
                          const float* __restrict__ cb, float* __restrict__ u) {
    int idx = blockIdx.x * 256 + threadIdx.x;        // over B*L*DI
    int d  = idx & (DI_ - 1);
    int bl = idx >> 10;                               // b*L + l
    int l  = bl & (L_ - 1);
    float acc = cb[d];
    #pragma unroll
    for (int k = 0; k < DC_; k++) {
        int lk = l - (DC_ - 1) + k;
        if (lk >= 0) acc = fmaf(xi[(size_t)(bl - (DC_ - 1) + k) * DI_ + d], cw[d * DC_ + k], acc);
    }
    u[idx] = acc * sigmoidf_(acc);
}

__global__ void xproj(const float* __restrict__ u, const float* __restrict__ W,
                      float* __restrict__ xdbl) {
    __shared__ float ur[DI_];
    const int m = blockIdx.x;
    const float* urow = u + (size_t)m * DI_;
    for (int i = threadIdx.x; i < DI_; i += 64) ur[i] = urow[i];
    __syncthreads();
    const int n = threadIdx.x;
    const float* wr = W + (size_t)n * DI_;
    float acc = 0.f;
    for (int k = 0; k < DI_; k += 4) {
        float4 w4 = *reinterpret_cast<const float4*>(wr + k);
        acc = fmaf(ur[k],     w4.x, acc);
        acc = fmaf(ur[k + 1], w4.y, acc);
        acc = fmaf(ur[k + 2], w4.z, acc);
        acc = fmaf(ur[k + 3], w4.w, acc);
    }
    xdbl[(size_t)m * NX_ + n] = acc;
}

__global__ void dt_proj(const float* __restrict__ xdbl, const float* __restrict__ Wdt,
                        const float* __restrict__ bdt, float* __restrict__ delta) {
    __shared__ float dt[DR_];
    int idx = blockIdx.x * 256 + threadIdx.x;
    int m = idx >> 10;
    int d = idx & (DI_ - 1);
    if (threadIdx.x < DR_) dt[threadIdx.x] = xdbl[(size_t)m * NX_ + threadIdx.x];
    __syncthreads();
    float acc = bdt[d];
    const float* wr = Wdt + d * DR_;
    #pragma unroll 8
    for (int r = 0; r < DR_; r++) acc = fmaf(dt[r], wr[r], acc);
    delta[idx] = fmaxf(acc, 0.f) + log1pf(__expf(-fabsf(acc)));   // softplus
}

__global__ void scan_p1(const float* __restrict__ delta, const float* __restrict__ u,
                        const float* __restrict__ xdbl, const float* __restrict__ A_log,
                        float* __restrict__ hz, float* __restrict__ pA) {
    const int d = blockIdx.x * 256 + threadIdx.x;
    const int c = blockIdx.y;
    const int b = blockIdx.z;
    __shared__ float Brow[CT_][DS_];
    for (int i = threadIdx.x; i < CT_ * DS_; i += 256) {
        int t = i >> 4, s = i & 15;
        Brow[t][s] = xdbl[(size_t)(b * L_ + c * CT_ + t) * NX_ + DR_ + s];
    }
    __syncthreads();
    float a[DS_], h[DS_], p[DS_];
    #pragma unroll
    for (int s = 0; s < DS_; s++) {
        a[s] = -__expf(A_log[d * DS_ + s]);
        h[s] = 0.f; p[s] = 1.f;
    }
    size_t base = (size_t)(b * L_ + c * CT_) * DI_ + d;
    for (int t = 0; t < CT_; t++) {
        float dl = delta[base + (size_t)t * DI_];
        float uv = u[base + (size_t)t * DI_];
        float dlu = dl * uv;
        #pragma unroll
        for (int s = 0; s < DS_; s++) {
            float dA = __expf(dl * a[s]);
            p[s] *= dA;
            h[s] = fmaf(dA, h[s], dlu * Brow[t][s]);
        }
    }
    size_t o = ((size_t)(b * NC_ + c) * DI_ + d) * DS_;
    #pragma unroll
    for (int s = 0; s < DS_; s++) { hz[o + s] = h[s]; pA[o + s] = p[s]; }
}

__global__ void carry(const float* __restrict__ hz, const float* __restrict__ pA,
                      float* __restrict__ hin) {
    int idx = blockIdx.x * 256 + threadIdx.x;    // over B*DI*DS
    int b  = idx >> 14;
    int ds = idx & (DI_ * DS_ - 1);
    float h = 0.f;
    for (int c = 0; c < NC_; c++) {
        size_t o = (size_t)(b * NC_ + c) * DI_ * DS_ + ds;
        hin[o] = h;
        h = fmaf(pA[o], h, hz[o]);
    }
}

__global__ void scan_p2(const float* __restrict__ delta, const float* __restrict__ u,
                        const float* __restrict__ xdbl, const float* __restrict__ A_log,
                        const float* __restrict__ hin, const float* __restrict__ z,
                        const float* __restrict__ Dp, float* __restrict__ yv) {
    const int d = blockIdx.x * 256 + threadIdx.x;
    const int c = blockIdx.y;
    const int b = blockIdx.z;
    __shared__ float Brow[CT_][DS_];
    __shared__ float Crow[CT_][DS_];
    for (int i = threadIdx.x; i < CT_ * DS_; i += 256) {
        int t = i >> 4, s = i & 15;
        size_t rb = (size_t)(b * L_ + c * CT_ + t) * NX_;
        Brow[t][s] = xdbl[rb + DR_ + s];
        Crow[t][s] = xdbl[rb + DR_ + DS_ + s];
    }
    __syncthreads();
    float a[DS_], h[DS_];
    size_t ho = ((size_t)(b * NC_ + c) * DI_ + d) * DS_;
    #pragma unroll
    for (int s = 0; s < DS_; s++) {
        a[s] = -__expf(A_log[d * DS_ + s]);
        h[s] = hin[ho + s];
    }
    float Dpd = Dp[d];
    size_t base = (size_t)(b * L_ + c * CT_) * DI_ + d;
    for (int t = 0; t < CT_; t++) {
        float dl = delta[base + (size_t)t * DI_];
        float uv = u[base + (size_t)t * DI_];
        float dlu = dl * uv;
        float acc = 0.f;
        #pragma unroll
        for (int s = 0; s < DS_; s++) {
            float dA = __expf(dl * a[s]);
            h[s] = fmaf(dA, h[s], dlu * Brow[t][s]);
            acc = fmaf(h[s], Crow[t][s], acc);
        }
        float zv = z[base + (size_t)t * DI_];
        float yval = fmaf(uv, Dpd, acc);
        yv[base + (size_t)t * DI_] = yval * (zv * sigmoidf_(zv));
    }
}

__global__ void ln_res(const float* __restrict__ om, const float* __restrict__ x,
                       const float* __restrict__ lw, const float* __restrict__ lb,
                       float* __restrict__ out) {
    const int row = blockIdx.x;                    // b*L
    const float* r = om + (size_t)row * D_;
    float v0 = r[threadIdx.x], v1 = r[threadIdx.x + 256];
    float s = v0 + v1, sq = v0 * v0 + v1 * v1;
    #pragma unroll
    for (int off = 32; off; off >>= 1) {
        s  += __shfl_down(s, off);
        sq += __shfl_down(sq, off);
    }
    __shared__ float ss[4], ssq[4];
    int w = threadIdx.x >> 6;
    if ((threadIdx.x & 63) == 0) { ss[w] = s; ssq[w] = sq; }
    __syncthreads();
    float ts  = ss[0] + ss[1] + ss[2] + ss[3];
    float tsq = ssq[0] + ssq[1] + ssq[2] + ssq[3];
    float mu  = ts * (1.f / 512.f);
    float var = tsq * (1.f / 512.f) - mu * mu;
    float inv = rsqrtf(var + 1e-6f);
    size_t i0 = (size_t)row * D_ + threadIdx.x;
    out[i0]       = x[i0]       + (v0 - mu) * inv * lw[threadIdx.x]       + lb[threadIdx.x];
    out[i0 + 256] = x[i0 + 256] + (v1 - mu) * inv * lw[threadIdx.x + 256] + lb[threadIdx.x + 256];
}

extern "C" void kernel_launch(void* const* d_in, const int* in_sizes, int n_in,
                              void* d_out, int out_size, void* d_ws, size_t ws_size,
                              hipStream_t stream) {
    const float* x      = (const float*)d_in[0];
    const float* W_in   = (const float*)d_in[1];
    const float* conv_w = (const float*)d_in[2];
    const float* conv_b = (const float*)d_in[3];
    const float* W_xp   = (const float*)d_in[4];
    const float* W_dt   = (const float*)d_in[5];
    const float* b_dt   = (const float*)d_in[6];
    const float* A_log  = (const float*)d_in[7];
    const float* Dp     = (const float*)d_in[8];
    const float* W_out  = (const float*)d_in[9];
    const float* ln_w   = (const float*)d_in[10];
    const float* ln_b   = (const float*)d_in[11];
    float* out = (float*)d_out;

    float* ws = (float*)d_ws;
    const size_t NBL = (size_t)B_ * L_ * DI_;          // 4,194,304
    float* xi    = ws;
    float* z     = xi + NBL;
    float* u     = z + NBL;
    float* delta = u + NBL;
    float* yv    = delta + NBL;
    float* xdbl  = yv + NBL;                           // B*L*NX
    float* hz    = xdbl + (size_t)B_ * L_ * NX_;
    float* pAb   = hz + (size_t)B_ * NC_ * DI_ * DS_;
    float* hin   = pAb + (size_t)B_ * NC_ * DI_ * DS_;
    float* om    = xi;                                  // xi dead after conv; reuse

    // bf16 staging buffers overlaid on dead/not-yet-live fp32 regions:
    // xb/wb live only until gemm1 (yv region not written until scan_p2)
    u16* xb  = (u16*)yv;                                // B*L*D  = 2M bf16 (4 MB)
    u16* wb  = xb + (size_t)B_ * L_ * D_;               // 2*DI*D = 1M bf16 (2 MB)
    // yvb/wob live after scan_p2 (delta dead by then)
    u16* yvb = (u16*)delta;                             // B*L*DI = 4M bf16 (8 MB)
    u16* wob = yvb + NBL;                               // D*DI   = 0.5M bf16 (1 MB)

    // 0. fp32 -> bf16 casts for GEMM1 operands
    cast_bf16<<<(int)(B_ * L_ * D_ / 8 / 256), 256, 0, stream>>>(x, xb, B_ * L_ * D_ / 8);
    cast_bf16<<<(2 * DI_ * D_ / 8 + 255) / 256, 256, 0, stream>>>(W_in, wb, 2 * DI_ * D_ / 8);
    // 1. in_proj (bf16 MFMA): [4096,512] x [2048,512]^T -> xi | z
    gemm_mfma_nt<512, 1024, 1024>
        <<<dim3(2048 / 128, 4096 / 128), 256, 0, stream>>>(xb, wb, xi, z);
    // 2. depthwise causal conv + SiLU
    conv_silu<<<(int)(NBL / 256), 256, 0, stream>>>(xi, conv_w, conv_b, u);
    // 3. x_proj: [4096,1024] x [64,1024]^T
    xproj<<<B_ * L_, 64, 0, stream>>>(u, W_xp, xdbl);
    // 4. dt_proj + softplus
    dt_proj<<<(int)(NBL / 256), 256, 0, stream>>>(xdbl, W_dt, b_dt, delta);
    // 5-7. chunked selective scan
    scan_p1<<<dim3(DI_ / 256, NC_, B_), 256, 0, stream>>>(delta, u, xdbl, A_log, hz, pAb);
    carry<<<(B_ * DI_ * DS_) / 256, 256, 0, stream>>>(hz, pAb, hin);
    scan_p2<<<dim3(DI_ / 256, NC_, B_), 256, 0, stream>>>(delta, u, xdbl, A_log, hin, z, Dp, yv);
    // 8. out_proj (bf16 MFMA): [4096,1024] x [512,1024]^T
    cast_bf16<<<(int)(NBL / 8 / 256), 256, 0, stream>>>(yv, yvb, (int)(NBL / 8));
    cast_bf16<<<(D_ * DI_ / 8 + 255) / 256, 256, 0, stream>>>(W_out, wob, D_ * DI_ / 8);
    gemm_mfma_nt<1024, 512, 512>
        <<<dim3(512 / 128, 4096 / 128), 256, 0, stream>>>(yvb, wob, om, om);
    // 9. LayerNorm + residual
    ln_res<<<B_ * L_, 256, 0, stream>>>(om, x, ln_w, ln_b, out);
}

// Round 3
// 206.165 us; speedup vs baseline: 2.6378x; 1.5390x over previous
//
#include <hip/hip_runtime.h>
#include <math.h>

#define B_  2
#define L_  2048
#define D_  512
#define DI_ 1024
#define DS_ 16
#define DC_ 4
#define DR_ 32
#define NX_ 64   // DR + 2*DS
#define NC_ 64   // number of scan chunks
#define CT_ 32   // chunk length (NC_*CT_ == L_)
#define KS_ 8    // xproj split-K factor

typedef unsigned short u16;
typedef u16   u16x8  __attribute__((ext_vector_type(8)));
typedef __bf16 bf16x8 __attribute__((ext_vector_type(8)));
typedef float  f32x4  __attribute__((ext_vector_type(4)));

__device__ __forceinline__ float sigmoidf_(float v) { return 1.f / (1.f + __expf(-v)); }

__device__ __forceinline__ u16 f2bf(float f) {
    union { float f; unsigned u; } c; c.f = f;
    unsigned u = c.u + 0x7FFFu + ((c.u >> 16) & 1u);
    return (u16)(u >> 16);
}

__global__ void cast_bf16(const float* __restrict__ in, u16* __restrict__ out, int n8) {
    int i = blockIdx.x * 256 + threadIdx.x;
    if (i >= n8) return;
    const float4* p = reinterpret_cast<const float4*>(in) + (size_t)i * 2;
    float4 v0 = p[0], v1 = p[1];
    u16x8 r;
    r[0] = f2bf(v0.x); r[1] = f2bf(v0.y); r[2] = f2bf(v0.z); r[3] = f2bf(v0.w);
    r[4] = f2bf(v1.x); r[5] = f2bf(v1.y); r[6] = f2bf(v1.z); r[7] = f2bf(v1.w);
    reinterpret_cast<u16x8*>(out)[i] = r;
}

// NT bf16 MFMA GEMM: C[m,n] = dot(A[m,:K], B[n,:K]). 128x128 tile, BK=64.
template<int K, int N0, int N1>
__global__ __launch_bounds__(256, 2) void gemm_mfma_nt(
    const u16* __restrict__ Ab, const u16* __restrict__ Bb,
    float* __restrict__ out0, float* __restrict__ out1) {
    __shared__ u16 As[128 * 64];
    __shared__ u16 Bs[128 * 64];
    const int bm = blockIdx.y * 128, bn = blockIdx.x * 128;
    const int t = threadIdx.x;
    const int w = t >> 6, l = t & 63;
    const int wm = (w >> 1) * 64, wn = (w & 1) * 64;
    const int lr = l & 15;
    const int lk = (l >> 4) * 8;

    f32x4 acc[4][4] = {};

    for (int k0 = 0; k0 < K; k0 += 64) {
        #pragma unroll
        for (int i = 0; i < 4; i++) {
            int q  = i * 256 + t;
            int r  = q >> 3;
            int c0 = ((q ^ r) & 7) << 3;
            __builtin_amdgcn_global_load_lds(
                (const __attribute__((address_space(1))) void*)(Ab + (size_t)(bm + r) * K + k0 + c0),
                (__attribute__((address_space(3))) void*)(As + (i * 256 + w * 64) * 8),
                16, 0, 0);
            __builtin_amdgcn_global_load_lds(
                (const __attribute__((address_space(1))) void*)(Bb + (size_t)(bn + r) * K + k0 + c0),
                (__attribute__((address_space(3))) void*)(Bs + (i * 256 + w * 64) * 8),
                16, 0, 0);
        }
        __syncthreads();
        #pragma unroll
        for (int kk = 0; kk < 2; kk++) {
            bf16x8 a[4], b[4];
            #pragma unroll
            for (int m = 0; m < 4; m++) {
                int row  = wm + m * 16 + lr;
                int byte = (row * 128 + (kk * 32 + lk) * 2) ^ ((row & 7) << 4);
                a[m] = *reinterpret_cast<const bf16x8*>(reinterpret_cast<const char*>(As) + byte);
            }
            #pragma unroll
            for (int n = 0; n < 4; n++) {
                int row  = wn + n * 16 + lr;
                int byte = (row * 128 + (kk * 32 + lk) * 2) ^ ((row & 7) << 4);
                b[n] = *reinterpret_cast<const bf16x8*>(reinterpret_cast<const char*>(Bs) + byte);
            }
            #pragma unroll
            for (int m = 0; m < 4; m++)
                #pragma unroll
                for (int n = 0; n < 4; n++)
                    acc[m][n] = __builtin_amdgcn_mfma_f32_16x16x32_bf16(a[m], b[n], acc[m][n], 0, 0, 0);
        }
        __syncthreads();
    }

    float* obase = (bn < N0) ? out0 : out1;
    const int stride = (bn < N0) ? N0 : N1;
    const int bcol   = (bn < N0) ? bn : bn - N0;
    #pragma unroll
    for (int m = 0; m < 4; m++) {
        #pragma unroll
        for (int j = 0; j < 4; j++) {
            int row = bm + wm + m * 16 + (l >> 4) * 4 + j;
            #pragma unroll
            for (int n = 0; n < 4; n++)
                obase[(size_t)row * stride + bcol + wn + n * 16 + lr] = acc[m][n][j];
        }
    }
}

// xproj as split-K MFMA: A=[4096][1024] bf16, B=[64][1024] bf16,
// tile 128(M)x64(N), BK=64, K-chunk = 1024/KS_. part[ks][4096][64] fp32.
__global__ __launch_bounds__(256, 2) void xproj_mfma(
    const u16* __restrict__ Ab, const u16* __restrict__ Bb, float* __restrict__ part) {
    __shared__ u16 As[128 * 64];
    __shared__ u16 Bs[64 * 64];
    const int ks = blockIdx.x;
    const int bm = blockIdx.y * 128;
    const int t = threadIdx.x;
    const int w = t >> 6, l = t & 63;
    const int wm = (w >> 1) * 64, wn = (w & 1) * 32;
    const int lr = l & 15;
    const int lk = (l >> 4) * 8;

    f32x4 acc[4][2] = {};

    for (int it = 0; it < (1024 / KS_) / 64; it++) {
        int k0 = ks * (1024 / KS_) + it * 64;
        #pragma unroll
        for (int i = 0; i < 4; i++) {
            int q  = i * 256 + t;
            int r  = q >> 3;
            int c0 = ((q ^ r) & 7) << 3;
            __builtin_amdgcn_global_load_lds(
                (const __attribute__((address_space(1))) void*)(Ab + (size_t)(bm + r) * 1024 + k0 + c0),
                (__attribute__((address_space(3))) void*)(As + (i * 256 + w * 64) * 8),
                16, 0, 0);
        }
        #pragma unroll
        for (int i = 0; i < 2; i++) {
            int q  = i * 256 + t;
            int r  = q >> 3;
            int c0 = ((q ^ r) & 7) << 3;
            __builtin_amdgcn_global_load_lds(
                (const __attribute__((address_space(1))) void*)(Bb + (size_t)r * 1024 + k0 + c0),
                (__attribute__((address_space(3))) void*)(Bs + (i * 256 + w * 64) * 8),
                16, 0, 0);
        }
        __syncthreads();
        #pragma unroll
        for (int kk = 0; kk < 2; kk++) {
            bf16x8 a[4], b[2];
            #pragma unroll
            for (int m = 0; m < 4; m++) {
                int row  = wm + m * 16 + lr;
                int byte = (row * 128 + (kk * 32 + lk) * 2) ^ ((row & 7) << 4);
                a[m] = *reinterpret_cast<const bf16x8*>(reinterpret_cast<const char*>(As) + byte);
            }
            #pragma unroll
            for (int n = 0; n < 2; n++) {
                int row  = wn + n * 16 + lr;
                int byte = (row * 128 + (kk * 32 + lk) * 2) ^ ((row & 7) << 4);
                b[n] = *reinterpret_cast<const bf16x8*>(reinterpret_cast<const char*>(Bs) + byte);
            }
            #pragma unroll
            for (int m = 0; m < 4; m++)
                #pragma unroll
                for (int n = 0; n < 2; n++)
                    acc[m][n] = __builtin_amdgcn_mfma_f32_16x16x32_bf16(a[m], b[n], acc[m][n], 0, 0, 0);
        }
        __syncthreads();
    }

    float* obase = part + (size_t)ks * (4096 * 64);
    #pragma unroll
    for (int m = 0; m < 4; m++) {
        #pragma unroll
        for (int j = 0; j < 4; j++) {
            int row = bm + wm + m * 16 + (l >> 4) * 4 + j;
            #pragma unroll
            for (int n = 0; n < 2; n++)
                obase[(size_t)row * 64 + wn + n * 16 + lr] = acc[m][n][j];
        }
    }
}

__global__ void xproj_reduce(const float* __restrict__ part, float* __restrict__ xdbl) {
    int i = blockIdx.x * 256 + threadIdx.x;    // over 4096*64
    float s = 0.f;
    #pragma unroll
    for (int ks = 0; ks < KS_; ks++) s += part[(size_t)ks * (4096 * 64) + i];
    xdbl[i] = s;
}

__global__ void conv_silu(const float* __restrict__ xi, const float* __restrict__ cw,
                          const float* __restrict__ cb, float* __restrict__ u,
                          u16* __restrict__ ub) {
    int idx = blockIdx.x * 256 + threadIdx.x;        // over B*L*DI
    int d  = idx & (DI_ - 1);
    int bl = idx >> 10;                               // b*L + l
    int l  = bl & (L_ - 1);
    float acc = cb[d];
    #pragma unroll
    for (int k = 0; k < DC_; k++) {
        int lk = l - (DC_ - 1) + k;
        if (lk >= 0) acc = fmaf(xi[(size_t)(bl - (DC_ - 1) + k) * DI_ + d], cw[d * DC_ + k], acc);
    }
    float v = acc * sigmoidf_(acc);
    u[idx]  = v;
    ub[idx] = f2bf(v);
}

__global__ void dt_proj(const float* __restrict__ xdbl, const float* __restrict__ Wdt,
                        const float* __restrict__ bdt, float* __restrict__ delta) {
    __shared__ float dt[DR_];
    int idx = blockIdx.x * 256 + threadIdx.x;
    int m = idx >> 10;
    int d = idx & (DI_ - 1);
    if (threadIdx.x < DR_) dt[threadIdx.x] = xdbl[(size_t)m * NX_ + threadIdx.x];
    __syncthreads();
    float acc = bdt[d];
    const float* wr = Wdt + d * DR_;
    #pragma unroll 8
    for (int r = 0; r < DR_; r++) acc = fmaf(dt[r], wr[r], acc);
    delta[idx] = fmaxf(acc, 0.f) + log1pf(__expf(-fabsf(acc)));   // softplus
}

__global__ void scan_p1(const float* __restrict__ delta, const float* __restrict__ u,
                        const float* __restrict__ xdbl, const float* __restrict__ A_log,
                        float* __restrict__ hz, float* __restrict__ pA) {
    const int d = blockIdx.x * 256 + threadIdx.x;
    const int c = blockIdx.y;
    const int b = blockIdx.z;
    __shared__ float Brow[CT_][DS_];
    for (int i = threadIdx.x; i < CT_ * DS_; i += 256) {
        int t = i >> 4, s = i & 15;
        Brow[t][s] = xdbl[(size_t)(b * L_ + c * CT_ + t) * NX_ + DR_ + s];
    }
    __syncthreads();
    float a[DS_], h[DS_], p[DS_];
    #pragma unroll
    for (int s = 0; s < DS_; s++) {
        a[s] = -__expf(A_log[d * DS_ + s]);
        h[s] = 0.f; p[s] = 1.f;
    }
    size_t base = (size_t)(b * L_ + c * CT_) * DI_ + d;
    for (int t = 0; t < CT_; t++) {
        float dl = delta[base + (size_t)t * DI_];
        float uv = u[base + (size_t)t * DI_];
        float dlu = dl * uv;
        #pragma unroll
        for (int s = 0; s < DS_; s++) {
            float dA = __expf(dl * a[s]);
            p[s] *= dA;
            h[s] = fmaf(dA, h[s], dlu * Brow[t][s]);
        }
    }
    size_t o = ((size_t)(b * NC_ + c) * DI_ + d) * DS_;
    #pragma unroll
    for (int s = 0; s < DS_; s++) { hz[o + s] = h[s]; pA[o + s] = p[s]; }
}

__global__ void carry(const float* __restrict__ hz, const float* __restrict__ pA,
                      float* __restrict__ hin) {
    int idx = blockIdx.x * 256 + threadIdx.x;    // over B*DI*DS
    int b  = idx >> 14;
    int ds = idx & (DI_ * DS_ - 1);
    float h = 0.f;
    for (int c = 0; c < NC_; c++) {
        size_t o = (size_t)(b * NC_ + c) * DI_ * DS_ + ds;
        hin[o] = h;
        h = fmaf(pA[o], h, hz[o]);
    }
}

__global__ void scan_p2(const float* __restrict__ delta, const float* __restrict__ u,
                        const float* __restrict__ xdbl, const float* __restrict__ A_log,
                        const float* __restrict__ hin, const float* __restrict__ z,
                        const float* __restrict__ Dp, u16* __restrict__ yvb) {
    const int d = blockIdx.x * 256 + threadIdx.x;
    const int c = blockIdx.y;
    const int b = blockIdx.z;
    __shared__ float Brow[CT_][DS_];
    __shared__ float Crow[CT_][DS_];
    for (int i = threadIdx.x; i < CT_ * DS_; i += 256) {
        int t = i >> 4, s = i & 15;
        size_t rb = (size_t)(b * L_ + c * CT_ + t) * NX_;
        Brow[t][s] = xdbl[rb + DR_ + s];
        Crow[t][s] = xdbl[rb + DR_ + DS_ + s];
    }
    __syncthreads();
    float a[DS_], h[DS_];
    size_t ho = ((size_t)(b * NC_ + c) * DI_ + d) * DS_;
    #pragma unroll
    for (int s = 0; s < DS_; s++) {
        a[s] = -__expf(A_log[d * DS_ + s]);
        h[s] = hin[ho + s];
    }
    float Dpd = Dp[d];
    size_t base = (size_t)(b * L_ + c * CT_) * DI_ + d;
    for (int t = 0; t < CT_; t++) {
        float dl = delta[base + (size_t)t * DI_];
        float uv = u[base + (size_t)t * DI_];
        float dlu = dl * uv;
        float acc = 0.f;
        #pragma unroll
        for (int s = 0; s < DS_; s++) {
            float dA = __expf(dl * a[s]);
            h[s] = fmaf(dA, h[s], dlu * Brow[t][s]);
            acc = fmaf(h[s], Crow[t][s], acc);
        }
        float zv = z[base + (size_t)t * DI_];
        float yval = fmaf(uv, Dpd, acc);
        yvb[base + (size_t)t * DI_] = f2bf(yval * (zv * sigmoidf_(zv)));
    }
}

__global__ void ln_res(const float* __restrict__ om, const float* __restrict__ x,
                       const float* __restrict__ lw, const float* __restrict__ lb,
                       float* __restrict__ out) {
    const int row = blockIdx.x;                    // b*L
    const float* r = om + (size_t)row * D_;
    float v0 = r[threadIdx.x], v1 = r[threadIdx.x + 256];
    float s = v0 + v1, sq = v0 * v0 + v1 * v1;
    #pragma unroll
    for (int off = 32; off; off >>= 1) {
        s  += __shfl_down(s, off);
        sq += __shfl_down(sq, off);
    }
    __shared__ float ss[4], ssq[4];
    int w = threadIdx.x >> 6;
    if ((threadIdx.x & 63) == 0) { ss[w] = s; ssq[w] = sq; }
    __syncthreads();
    float ts  = ss[0] + ss[1] + ss[2] + ss[3];
    float tsq = ssq[0] + ssq[1] + ssq[2] + ssq[3];
    float mu  = ts * (1.f / 512.f);
    float var = tsq * (1.f / 512.f) - mu * mu;
    float inv = rsqrtf(var + 1e-6f);
    size_t i0 = (size_t)row * D_ + threadIdx.x;
    out[i0]       = x[i0]       + (v0 - mu) * inv * lw[threadIdx.x]       + lb[threadIdx.x];
    out[i0 + 256] = x[i0 + 256] + (v1 - mu) * inv * lw[threadIdx.x + 256] + lb[threadIdx.x + 256];
}

extern "C" void kernel_launch(void* const* d_in, const int* in_sizes, int n_in,
                              void* d_out, int out_size, void* d_ws, size_t ws_size,
                              hipStream_t stream) {
    const float* x      = (const float*)d_in[0];
    const float* W_in   = (const float*)d_in[1];
    const float* conv_w = (const float*)d_in[2];
    const float* conv_b = (const float*)d_in[3];
    const float* W_xp   = (const float*)d_in[4];
    const float* W_dt   = (const float*)d_in[5];
    const float* b_dt   = (const float*)d_in[6];
    const float* A_log  = (const float*)d_in[7];
    const float* Dp     = (const float*)d_in[8];
    const float* W_out  = (const float*)d_in[9];
    const float* ln_w   = (const float*)d_in[10];
    const float* ln_b   = (const float*)d_in[11];
    float* out = (float*)d_out;

    float* ws = (float*)d_ws;
    const size_t NBL = (size_t)B_ * L_ * DI_;          // 4,194,304
    float* xi    = ws;
    float* z     = xi + NBL;
    float* u     = z + NBL;
    float* delta = u + NBL;
    float* yvr   = delta + NBL;                        // NBL floats (reused region)
    float* xdbl  = yvr + NBL;                          // B*L*NX
    float* hz    = xdbl + (size_t)B_ * L_ * NX_;       // NC scan partials
    float* pAb   = hz + (size_t)B_ * NC_ * DI_ * DS_;
    float* hin   = pAb + (size_t)B_ * NC_ * DI_ * DS_;
    float* om    = xi;                                  // xi dead after conv; reuse

    // bf16 / partial overlays on temporally-dead fp32 regions:
    u16* xb   = (u16*)yvr;                     // gemm1 A (lives: cast -> gemm1)
    u16* wb   = xb + (size_t)B_ * L_ * D_;     // gemm1 B
    u16* yvb  = (u16*)yvr;                     // gemm2 A (written by scan_p2, after gemm1)
    u16* wob  = yvb + NBL;                     // gemm2 B (yv region second half)
    u16* ub   = (u16*)hin;                     // bf16 u  (lives: conv -> xproj_mfma; hin written later)
    u16* wxb  = (u16*)pAb;                     // bf16 W_xp (lives until xproj_mfma; pA written later)
    float* part = hz;                          // xproj partials [KS][4096][64] (hz written later)

    // 0. fp32 -> bf16 casts
    cast_bf16<<<(int)(B_ * L_ * D_ / 8 / 256), 256, 0, stream>>>(x, xb, B_ * L_ * D_ / 8);
    cast_bf16<<<(2 * DI_ * D_ / 8 + 255) / 256, 256, 0, stream>>>(W_in, wb, 2 * DI_ * D_ / 8);
    cast_bf16<<<(64 * 1024 / 8 + 255) / 256, 256, 0, stream>>>(W_xp, wxb, 64 * 1024 / 8);
    cast_bf16<<<(D_ * DI_ / 8 + 255) / 256, 256, 0, stream>>>(W_out, wob, D_ * DI_ / 8);
    // 1. in_proj (bf16 MFMA): [4096,512] x [2048,512]^T -> xi | z
    gemm_mfma_nt<512, 1024, 1024>
        <<<dim3(2048 / 128, 4096 / 128), 256, 0, stream>>>(xb, wb, xi, z);
    // 2. depthwise causal conv + SiLU (+ bf16 copy of u)
    conv_silu<<<(int)(NBL / 256), 256, 0, stream>>>(xi, conv_w, conv_b, u, ub);
    // 3. x_proj as split-K MFMA + reduce
    xproj_mfma<<<dim3(KS_, 4096 / 128), 256, 0, stream>>>(ub, wxb, part);
    xproj_reduce<<<4096 * 64 / 256, 256, 0, stream>>>(part, xdbl);
    // 4. dt_proj + softplus
    dt_proj<<<(int)(NBL / 256), 256, 0, stream>>>(xdbl, W_dt, b_dt, delta);
    // 5-7. chunked selective scan
    scan_p1<<<dim3(DI_ / 256, NC_, B_), 256, 0, stream>>>(delta, u, xdbl, A_log, hz, pAb);
    carry<<<(B_ * DI_ * DS_) / 256, 256, 0, stream>>>(hz, pAb, hin);
    scan_p2<<<dim3(DI_ / 256, NC_, B_), 256, 0, stream>>>(delta, u, xdbl, A_log, hin, z, Dp, yvb);
    // 8. out_proj (bf16 MFMA): [4096,1024] x [512,1024]^T
    gemm_mfma_nt<1024, 512, 512>
        <<<dim3(512 / 128, 4096 / 128), 256, 0, stream>>>(yvb, wob, om, om);
    // 9. LayerNorm + residual
    ln_res<<<B_ * L_, 256, 0, stream>>>(om, x, ln_w, ln_b, out);
}

// Round 4
// 158.179 us; speedup vs baseline: 3.4381x; 1.3034x over previous
//
#include <hip/hip_runtime.h>
#include <math.h>

#define B_  2
#define L_  2048
#define D_  512
#define DI_ 1024
#define DS_ 16
#define DC_ 4
#define DR_ 32
#define NX_ 64   // DR + 2*DS
#define NC_ 64   // number of scan chunks
#define CT_ 32   // chunk length (NC_*CT_ == L_)
#define KS_ 8    // xproj split-K factor
#define MC_ 32   // dt_proj m-tile

typedef unsigned short u16;
typedef u16   u16x8  __attribute__((ext_vector_type(8)));
typedef __bf16 bf16x8 __attribute__((ext_vector_type(8)));
typedef float  f32x4  __attribute__((ext_vector_type(4)));

__device__ __forceinline__ float sigmoidf_(float v) { return 1.f / (1.f + __expf(-v)); }

__device__ __forceinline__ u16 f2bf(float f) {
    union { float f; unsigned u; } c; c.f = f;
    unsigned u = c.u + 0x7FFFu + ((c.u >> 16) & 1u);
    return (u16)(u >> 16);
}

__global__ void cast_bf16(const float* __restrict__ in, u16* __restrict__ out, int n8) {
    int i = blockIdx.x * 256 + threadIdx.x;
    if (i >= n8) return;
    const float4* p = reinterpret_cast<const float4*>(in) + (size_t)i * 2;
    float4 v0 = p[0], v1 = p[1];
    u16x8 r;
    r[0] = f2bf(v0.x); r[1] = f2bf(v0.y); r[2] = f2bf(v0.z); r[3] = f2bf(v0.w);
    r[4] = f2bf(v1.x); r[5] = f2bf(v1.y); r[6] = f2bf(v1.z); r[7] = f2bf(v1.w);
    reinterpret_cast<u16x8*>(out)[i] = r;
}

// NT bf16 MFMA GEMM: C[m,n] = dot(A[m,:K], B[n,:K]). 128x128 tile, BK=64.
template<int K, int N0, int N1>
__global__ __launch_bounds__(256, 2) void gemm_mfma_nt(
    const u16* __restrict__ Ab, const u16* __restrict__ Bb,
    float* __restrict__ out0, float* __restrict__ out1) {
    __shared__ u16 As[128 * 64];
    __shared__ u16 Bs[128 * 64];
    const int bm = blockIdx.y * 128, bn = blockIdx.x * 128;
    const int t = threadIdx.x;
    const int w = t >> 6, l = t & 63;
    const int wm = (w >> 1) * 64, wn = (w & 1) * 64;
    const int lr = l & 15;
    const int lk = (l >> 4) * 8;

    f32x4 acc[4][4] = {};

    for (int k0 = 0; k0 < K; k0 += 64) {
        #pragma unroll
        for (int i = 0; i < 4; i++) {
            int q  = i * 256 + t;
            int r  = q >> 3;
            int c0 = ((q ^ r) & 7) << 3;
            __builtin_amdgcn_global_load_lds(
                (const __attribute__((address_space(1))) void*)(Ab + (size_t)(bm + r) * K + k0 + c0),
                (__attribute__((address_space(3))) void*)(As + (i * 256 + w * 64) * 8),
                16, 0, 0);
            __builtin_amdgcn_global_load_lds(
                (const __attribute__((address_space(1))) void*)(Bb + (size_t)(bn + r) * K + k0 + c0),
                (__attribute__((address_space(3))) void*)(Bs + (i * 256 + w * 64) * 8),
                16, 0, 0);
        }
        __syncthreads();
        #pragma unroll
        for (int kk = 0; kk < 2; kk++) {
            bf16x8 a[4], b[4];
            #pragma unroll
            for (int m = 0; m < 4; m++) {
                int row  = wm + m * 16 + lr;
                int byte = (row * 128 + (kk * 32 + lk) * 2) ^ ((row & 7) << 4);
                a[m] = *reinterpret_cast<const bf16x8*>(reinterpret_cast<const char*>(As) + byte);
            }
            #pragma unroll
            for (int n = 0; n < 4; n++) {
                int row  = wn + n * 16 + lr;
                int byte = (row * 128 + (kk * 32 + lk) * 2) ^ ((row & 7) << 4);
                b[n] = *reinterpret_cast<const bf16x8*>(reinterpret_cast<const char*>(Bs) + byte);
            }
            #pragma unroll
            for (int m = 0; m < 4; m++)
                #pragma unroll
                for (int n = 0; n < 4; n++)
                    acc[m][n] = __builtin_amdgcn_mfma_f32_16x16x32_bf16(a[m], b[n], acc[m][n], 0, 0, 0);
        }
        __syncthreads();
    }

    float* obase = (bn < N0) ? out0 : out1;
    const int stride = (bn < N0) ? N0 : N1;
    const int bcol   = (bn < N0) ? bn : bn - N0;
    #pragma unroll
    for (int m = 0; m < 4; m++) {
        #pragma unroll
        for (int j = 0; j < 4; j++) {
            int row = bm + wm + m * 16 + (l >> 4) * 4 + j;
            #pragma unroll
            for (int n = 0; n < 4; n++)
                obase[(size_t)row * stride + bcol + wn + n * 16 + lr] = acc[m][n][j];
        }
    }
}

// xproj as split-K MFMA: A=[4096][1024] bf16, B=[64][1024] bf16,
// tile 128(M)x64(N), BK=64, K-chunk = 1024/KS_. part[ks][4096][64] fp32.
__global__ __launch_bounds__(256, 2) void xproj_mfma(
    const u16* __restrict__ Ab, const u16* __restrict__ Bb, float* __restrict__ part) {
    __shared__ u16 As[128 * 64];
    __shared__ u16 Bs[64 * 64];
    const int ks = blockIdx.x;
    const int bm = blockIdx.y * 128;
    const int t = threadIdx.x;
    const int w = t >> 6, l = t & 63;
    const int wm = (w >> 1) * 64, wn = (w & 1) * 32;
    const int lr = l & 15;
    const int lk = (l >> 4) * 8;

    f32x4 acc[4][2] = {};

    for (int it = 0; it < (1024 / KS_) / 64; it++) {
        int k0 = ks * (1024 / KS_) + it * 64;
        #pragma unroll
        for (int i = 0; i < 4; i++) {
            int q  = i * 256 + t;
            int r  = q >> 3;
            int c0 = ((q ^ r) & 7) << 3;
            __builtin_amdgcn_global_load_lds(
                (const __attribute__((address_space(1))) void*)(Ab + (size_t)(bm + r) * 1024 + k0 + c0),
                (__attribute__((address_space(3))) void*)(As + (i * 256 + w * 64) * 8),
                16, 0, 0);
        }
        #pragma unroll
        for (int i = 0; i < 2; i++) {
            int q  = i * 256 + t;
            int r  = q >> 3;
            int c0 = ((q ^ r) & 7) << 3;
            __builtin_amdgcn_global_load_lds(
                (const __attribute__((address_space(1))) void*)(Bb + (size_t)r * 1024 + k0 + c0),
                (__attribute__((address_space(3))) void*)(Bs + (i * 256 + w * 64) * 8),
                16, 0, 0);
        }
        __syncthreads();
        #pragma unroll
        for (int kk = 0; kk < 2; kk++) {
            bf16x8 a[4], b[2];
            #pragma unroll
            for (int m = 0; m < 4; m++) {
                int row  = wm + m * 16 + lr;
                int byte = (row * 128 + (kk * 32 + lk) * 2) ^ ((row & 7) << 4);
                a[m] = *reinterpret_cast<const bf16x8*>(reinterpret_cast<const char*>(As) + byte);
            }
            #pragma unroll
            for (int n = 0; n < 2; n++) {
                int row  = wn + n * 16 + lr;
                int byte = (row * 128 + (kk * 32 + lk) * 2) ^ ((row & 7) << 4);
                b[n] = *reinterpret_cast<const bf16x8*>(reinterpret_cast<const char*>(Bs) + byte);
            }
            #pragma unroll
            for (int m = 0; m < 4; m++)
                #pragma unroll
                for (int n = 0; n < 2; n++)
                    acc[m][n] = __builtin_amdgcn_mfma_f32_16x16x32_bf16(a[m], b[n], acc[m][n], 0, 0, 0);
        }
        __syncthreads();
    }

    float* obase = part + (size_t)ks * (4096 * 64);
    #pragma unroll
    for (int m = 0; m < 4; m++) {
        #pragma unroll
        for (int j = 0; j < 4; j++) {
            int row = bm + wm + m * 16 + (l >> 4) * 4 + j;
            #pragma unroll
            for (int n = 0; n < 2; n++)
                obase[(size_t)row * 64 + wn + n * 16 + lr] = acc[m][n][j];
        }
    }
}

__global__ void xproj_reduce(const float* __restrict__ part, float* __restrict__ xdbl) {
    int i = blockIdx.x * 256 + threadIdx.x;    // over 4096*64
    float s = 0.f;
    #pragma unroll
    for (int ks = 0; ks < KS_; ks++) s += part[(size_t)ks * (4096 * 64) + i];
    xdbl[i] = s;
}

__global__ void conv_silu(const float* __restrict__ xi, const float* __restrict__ cw,
                          const float* __restrict__ cb, float* __restrict__ u,
                          u16* __restrict__ ub) {
    int idx = blockIdx.x * 256 + threadIdx.x;        // over B*L*DI
    int d  = idx & (DI_ - 1);
    int bl = idx >> 10;                               // b*L + l
    int l  = bl & (L_ - 1);
    float acc = cb[d];
    #pragma unroll
    for (int k = 0; k < DC_; k++) {
        int lk = l - (DC_ - 1) + k;
        if (lk >= 0) acc = fmaf(xi[(size_t)(bl - (DC_ - 1) + k) * DI_ + d], cw[d * DC_ + k], acc);
    }
    float v = acc * sigmoidf_(acc);
    u[idx]  = v;
    ub[idx] = f2bf(v);
}

// delta = softplus(xdbl[:, :DR] @ W_dt^T + b_dt), tiled:
// block = 256 d's x MC_ m's; W rows staged coalesced into padded LDS then
// hoisted to 32 VGPRs; dt rows broadcast from LDS.
__global__ __launch_bounds__(256) void dt_proj_tiled(
    const float* __restrict__ xdbl, const float* __restrict__ Wdt,
    const float* __restrict__ bdt, float* __restrict__ delta) {
    __shared__ float Wl[256 * 33];
    __shared__ float dts[MC_][DR_];
    const int t  = threadIdx.x;
    const int d0 = blockIdx.x * 256;
    const int m0 = blockIdx.y * MC_;

    // coalesced stage of W_dt rows [d0, d0+256) -> padded LDS
    {
        const float4* src = reinterpret_cast<const float4*>(Wdt + (size_t)d0 * DR_);
        #pragma unroll
        for (int i = 0; i < 8; i++) {
            int e = (i * 256 + t);            // float4 index within 256*32
            int r4 = e & 7, row = e >> 3;
            float4 v = src[e];
            float* dst = &Wl[row * 33 + r4 * 4];
            dst[0] = v.x; dst[1] = v.y; dst[2] = v.z; dst[3] = v.w;
        }
    }
    // stage dt rows [m0, m0+MC_), cols 0..31
    for (int i = t; i < MC_ * DR_; i += 256) {
        int m = i >> 5, r = i & 31;
        dts[m][r] = xdbl[(size_t)(m0 + m) * NX_ + r];
    }
    __syncthreads();

    // hoist this thread's W row into registers (conflict-free: bank = (t+r)&31)
    float wreg[DR_];
    #pragma unroll
    for (int r = 0; r < DR_; r++) wreg[r] = Wl[t * 33 + r];
    const float bias = bdt[d0 + t];

    for (int m = 0; m < MC_; m++) {
        float a0 = bias, a1 = 0.f, a2 = 0.f, a3 = 0.f;
        #pragma unroll
        for (int r = 0; r < DR_; r += 4) {
            a0 = fmaf(dts[m][r],     wreg[r],     a0);
            a1 = fmaf(dts[m][r + 1], wreg[r + 1], a1);
            a2 = fmaf(dts[m][r + 2], wreg[r + 2], a2);
            a3 = fmaf(dts[m][r + 3], wreg[r + 3], a3);
        }
        float acc = (a0 + a1) + (a2 + a3);
        float sp  = fmaxf(acc, 0.f) + __logf(1.f + __expf(-fabsf(acc)));
        delta[(size_t)(m0 + m) * DI_ + d0 + t] = sp;
    }
}

__global__ void scan_p1(const float* __restrict__ delta, const float* __restrict__ u,
                        const float* __restrict__ xdbl, const float* __restrict__ A_log,
                        float* __restrict__ hz, float* __restrict__ pA) {
    const int d = blockIdx.x * 256 + threadIdx.x;
    const int c = blockIdx.y;
    const int b = blockIdx.z;
    __shared__ float Brow[CT_][DS_];
    for (int i = threadIdx.x; i < CT_ * DS_; i += 256) {
        int t = i >> 4, s = i & 15;
        Brow[t][s] = xdbl[(size_t)(b * L_ + c * CT_ + t) * NX_ + DR_ + s];
    }
    __syncthreads();
    float a[DS_], h[DS_], p[DS_];
    #pragma unroll
    for (int s = 0; s < DS_; s++) {
        a[s] = -__expf(A_log[d * DS_ + s]);
        h[s] = 0.f; p[s] = 1.f;
    }
    size_t base = (size_t)(b * L_ + c * CT_) * DI_ + d;
    for (int t = 0; t < CT_; t++) {
        float dl = delta[base + (size_t)t * DI_];
        float uv = u[base + (size_t)t * DI_];
        float dlu = dl * uv;
        #pragma unroll
        for (int s = 0; s < DS_; s++) {
            float dA = __expf(dl * a[s]);
            p[s] *= dA;
            h[s] = fmaf(dA, h[s], dlu * Brow[t][s]);
        }
    }
    size_t o = ((size_t)(b * NC_ + c) * DI_ + d) * DS_;
    #pragma unroll
    for (int s = 0; s < DS_; s++) { hz[o + s] = h[s]; pA[o + s] = p[s]; }
}

__global__ void carry(const float* __restrict__ hz, const float* __restrict__ pA,
                      float* __restrict__ hin) {
    int idx = blockIdx.x * 256 + threadIdx.x;    // over B*DI*DS
    int b  = idx >> 14;
    int ds = idx & (DI_ * DS_ - 1);
    float h = 0.f;
    for (int c = 0; c < NC_; c++) {
        size_t o = (size_t)(b * NC_ + c) * DI_ * DS_ + ds;
        hin[o] = h;
        h = fmaf(pA[o], h, hz[o]);
    }
}

__global__ void scan_p2(const float* __restrict__ delta, const float* __restrict__ u,
                        const float* __restrict__ xdbl, const float* __restrict__ A_log,
                        const float* __restrict__ hin, const float* __restrict__ z,
                        const float* __restrict__ Dp, u16* __restrict__ yvb) {
    const int d = blockIdx.x * 256 + threadIdx.x;
    const int c = blockIdx.y;
    const int b = blockIdx.z;
    __shared__ float Brow[CT_][DS_];
    __shared__ float Crow[CT_][DS_];
    for (int i = threadIdx.x; i < CT_ * DS_; i += 256) {
        int t = i >> 4, s = i & 15;
        size_t rb = (size_t)(b * L_ + c * CT_ + t) * NX_;
        Brow[t][s] = xdbl[rb + DR_ + s];
        Crow[t][s] = xdbl[rb + DR_ + DS_ + s];
    }
    __syncthreads();
    float a[DS_], h[DS_];
    size_t ho = ((size_t)(b * NC_ + c) * DI_ + d) * DS_;
    #pragma unroll
    for (int s = 0; s < DS_; s++) {
        a[s] = -__expf(A_log[d * DS_ + s]);
        h[s] = hin[ho + s];
    }
    float Dpd = Dp[d];
    size_t base = (size_t)(b * L_ + c * CT_) * DI_ + d;
    for (int t = 0; t < CT_; t++) {
        float dl = delta[base + (size_t)t * DI_];
        float uv = u[base + (size_t)t * DI_];
        float dlu = dl * uv;
        float acc = 0.f;
        #pragma unroll
        for (int s = 0; s < DS_; s++) {
            float dA = __expf(dl * a[s]);
            h[s] = fmaf(dA, h[s], dlu * Brow[t][s]);
            acc = fmaf(h[s], Crow[t][s], acc);
        }
        float zv = z[base + (size_t)t * DI_];
        float yval = fmaf(uv, Dpd, acc);
        yvb[base + (size_t)t * DI_] = f2bf(yval * (zv * sigmoidf_(zv)));
    }
}

__global__ void ln_res(const float* __restrict__ om, const float* __restrict__ x,
                       const float* __restrict__ lw, const float* __restrict__ lb,
                       float* __restrict__ out) {
    const int row = blockIdx.x;                    // b*L
    const float* r = om + (size_t)row * D_;
    float v0 = r[threadIdx.x], v1 = r[threadIdx.x + 256];
    float s = v0 + v1, sq = v0 * v0 + v1 * v1;
    #pragma unroll
    for (int off = 32; off; off >>= 1) {
        s  += __shfl_down(s, off);
        sq += __shfl_down(sq, off);
    }
    __shared__ float ss[4], ssq[4];
    int w = threadIdx.x >> 6;
    if ((threadIdx.x & 63) == 0) { ss[w] = s; ssq[w] = sq; }
    __syncthreads();
    float ts  = ss[0] + ss[1] + ss[2] + ss[3];
    float tsq = ssq[0] + ssq[1] + ssq[2] + ssq[3];
    float mu  = ts * (1.f / 512.f);
    float var = tsq * (1.f / 512.f) - mu * mu;
    float inv = rsqrtf(var + 1e-6f);
    size_t i0 = (size_t)row * D_ + threadIdx.x;
    out[i0]       = x[i0]       + (v0 - mu) * inv * lw[threadIdx.x]       + lb[threadIdx.x];
    out[i0 + 256] = x[i0 + 256] + (v1 - mu) * inv * lw[threadIdx.x + 256] + lb[threadIdx.x + 256];
}

extern "C" void kernel_launch(void* const* d_in, const int* in_sizes, int n_in,
                              void* d_out, int out_size, void* d_ws, size_t ws_size,
                              hipStream_t stream) {
    const float* x      = (const float*)d_in[0];
    const float* W_in   = (const float*)d_in[1];
    const float* conv_w = (const float*)d_in[2];
    const float* conv_b = (const float*)d_in[3];
    const float* W_xp   = (const float*)d_in[4];
    const float* W_dt   = (const float*)d_in[5];
    const float* b_dt   = (const float*)d_in[6];
    const float* A_log  = (const float*)d_in[7];
    const float* Dp     = (const float*)d_in[8];
    const float* W_out  = (const float*)d_in[9];
    const float* ln_w   = (const float*)d_in[10];
    const float* ln_b   = (const float*)d_in[11];
    float* out = (float*)d_out;

    float* ws = (float*)d_ws;
    const size_t NBL = (size_t)B_ * L_ * DI_;          // 4,194,304
    float* xi    = ws;
    float* z     = xi + NBL;
    float* u     = z + NBL;
    float* delta = u + NBL;
    float* yvr   = delta + NBL;                        // NBL floats (reused region)
    float* xdbl  = yvr + NBL;                          // B*L*NX
    float* hz    = xdbl + (size_t)B_ * L_ * NX_;       // NC scan partials
    float* pAb   = hz + (size_t)B_ * NC_ * DI_ * DS_;
    float* hin   = pAb + (size_t)B_ * NC_ * DI_ * DS_;
    float* om    = xi;                                  // xi dead after conv; reuse

    // bf16 / partial overlays on temporally-dead fp32 regions:
    u16* xb   = (u16*)yvr;                     // gemm1 A (lives: cast -> gemm1)
    u16* wb   = xb + (size_t)B_ * L_ * D_;     // gemm1 B
    u16* yvb  = (u16*)yvr;                     // gemm2 A (written by scan_p2, after gemm1)
    u16* wob  = yvb + NBL;                     // gemm2 B (yv region second half)
    u16* ub   = (u16*)hin;                     // bf16 u  (lives: conv -> xproj_mfma; hin written later)
    u16* wxb  = (u16*)pAb;                     // bf16 W_xp (lives until xproj_mfma; pA written later)
    float* part = hz;                          // xproj partials [KS][4096][64] (hz written later)

    // 0. fp32 -> bf16 casts
    cast_bf16<<<(int)(B_ * L_ * D_ / 8 / 256), 256, 0, stream>>>(x, xb, B_ * L_ * D_ / 8);
    cast_bf16<<<(2 * DI_ * D_ / 8 + 255) / 256, 256, 0, stream>>>(W_in, wb, 2 * DI_ * D_ / 8);
    cast_bf16<<<(64 * 1024 / 8 + 255) / 256, 256, 0, stream>>>(W_xp, wxb, 64 * 1024 / 8);
    cast_bf16<<<(D_ * DI_ / 8 + 255) / 256, 256, 0, stream>>>(W_out, wob, D_ * DI_ / 8);
    // 1. in_proj (bf16 MFMA): [4096,512] x [2048,512]^T -> xi | z
    gemm_mfma_nt<512, 1024, 1024>
        <<<dim3(2048 / 128, 4096 / 128), 256, 0, stream>>>(xb, wb, xi, z);
    // 2. depthwise causal conv + SiLU (+ bf16 copy of u)
    conv_silu<<<(int)(NBL / 256), 256, 0, stream>>>(xi, conv_w, conv_b, u, ub);
    // 3. x_proj as split-K MFMA + reduce
    xproj_mfma<<<dim3(KS_, 4096 / 128), 256, 0, stream>>>(ub, wxb, part);
    xproj_reduce<<<4096 * 64 / 256, 256, 0, stream>>>(part, xdbl);
    // 4. dt_proj + softplus (tiled, LDS-staged W)
    dt_proj_tiled<<<dim3(DI_ / 256, (B_ * L_) / MC_), 256, 0, stream>>>(xdbl, W_dt, b_dt, delta);
    // 5-7. chunked selective scan
    scan_p1<<<dim3(DI_ / 256, NC_, B_), 256, 0, stream>>>(delta, u, xdbl, A_log, hz, pAb);
    carry<<<(B_ * DI_ * DS_) / 256, 256, 0, stream>>>(hz, pAb, hin);
    scan_p2<<<dim3(DI_ / 256, NC_, B_), 256, 0, stream>>>(delta, u, xdbl, A_log, hin, z, Dp, yvb);
    // 8. out_proj (bf16 MFMA): [4096,1024] x [512,1024]^T
    gemm_mfma_nt<1024, 512, 512>
        <<<dim3(512 / 128, 4096 / 128), 256, 0, stream>>>(yvb, wob, om, om);
    // 9. LayerNorm + residual
    ln_res<<<B_ * L_, 256, 0, stream>>>(om, x, ln_w, ln_b, out);
}